// Round 1
// baseline (1559.931 us; speedup 1.0000x reference)
//
#include <hip/hip_runtime.h>
#include <math.h>

#pragma STDC FP_CONTRACT OFF

#define N 6000
#define C 81
#define PADDING 300
#define NMS_THRESH 0.5f
#define MASK_ELEMS (14 * 14 * 81) /* 15876 */

// ---------------------------------------------------------------------------
// Kernel 1: per-proposal decode.
// For each proposal: argmax class over all C (first-occurrence), max score
// over classes 1..C-1 (NMS score), decode the top class's box, clip.
// ---------------------------------------------------------------------------
__global__ void decode_kernel(const float* __restrict__ meta,
                              const float* __restrict__ deltas,
                              const float* __restrict__ proposals,
                              const float* __restrict__ scores,
                              float* __restrict__ pbox,
                              float* __restrict__ maxs) {
    int n = blockIdx.x * blockDim.x + threadIdx.x;
    if (n >= N) return;

    float Hm = meta[0], Wm = meta[1], scale = meta[2];

    float b0 = proposals[n * 4 + 0] / scale;
    float b1 = proposals[n * 4 + 1] / scale;
    float b2 = proposals[n * 4 + 2] / scale;
    float b3 = proposals[n * 4 + 3] / scale;
    float w = b2 - b0 + 1.0f;
    float h = b3 - b1 + 1.0f;
    float cx = b0 + 0.5f * w;
    float cy = b1 + 0.5f * h;

    const float* sr = scores + n * C;
    int top = 0;
    float best = sr[0];
    float ms = -INFINITY;  // max over classes 1..C-1
    for (int c = 1; c < C; ++c) {
        float s = sr[c];
        if (s > best) { best = s; top = c; }  // strict > == first occurrence
        ms = fmaxf(ms, s);
    }

    const float* dr = deltas + n * (4 * C) + 4 * top;
    float dx = dr[0], dy = dr[1], dw = dr[2], dh = dr[3];
    float pcx = dx * w + cx;
    float pcy = dy * h + cy;
    float pw = expf(dw) * w;
    float ph = expf(dh) * h;
    float x1 = pcx - 0.5f * pw;
    float y1 = pcy - 0.5f * ph;
    float x2 = pcx + 0.5f * pw;
    float y2 = pcy + 0.5f * ph;
    x1 = fminf(fmaxf(x1, 0.0f), Wm - 1.0f);
    y1 = fminf(fmaxf(y1, 0.0f), Hm - 1.0f);
    x2 = fminf(fmaxf(x2, 0.0f), Wm - 1.0f);
    y2 = fminf(fmaxf(y2, 0.0f), Hm - 1.0f);

    pbox[n * 4 + 0] = x1;
    pbox[n * 4 + 1] = y1;
    pbox[n * 4 + 2] = x2;
    pbox[n * 4 + 3] = y2;
    maxs[n] = ms;
}

// ---------------------------------------------------------------------------
// Kernel 2: greedy NMS, single block of 1024 threads (16 waves).
// Scores in LDS; each thread keeps up to 6 boxes in registers.
// Exactly PADDING iterations, matching jax.lax.scan semantics:
//   i = argmax(s) (first occurrence), valid = s[i] > -inf,
//   suppress winner + all IoU > thresh, even when invalid.
// ---------------------------------------------------------------------------
__global__ void __launch_bounds__(1024) nms_kernel(const float* __restrict__ pbox,
                                                   const float* __restrict__ maxs,
                                                   int* __restrict__ out_idx,
                                                   float* __restrict__ out_valid) {
    __shared__ float ssc[N];
    __shared__ float rs[16];
    __shared__ int ri[16];
    __shared__ int swin;

    int tid = threadIdx.x;

    float x1[6], y1[6], x2[6], y2[6], ar[6];
#pragma unroll
    for (int k = 0; k < 6; ++k) {
        int j = tid + k * 1024;
        if (j < N) {
            x1[k] = pbox[j * 4 + 0];
            y1[k] = pbox[j * 4 + 1];
            x2[k] = pbox[j * 4 + 2];
            y2[k] = pbox[j * 4 + 3];
            ar[k] = (x2[k] - x1[k] + 1.0f) * (y2[k] - y1[k] + 1.0f);
            ssc[j] = maxs[j];
        }
    }
    __syncthreads();

    for (int t = 0; t < PADDING; ++t) {
        // local argmax (first-occurrence tie-break: lower index wins ties)
        float bs = -INFINITY;
        int bi = 0x7fffffff;
#pragma unroll
        for (int k = 0; k < 6; ++k) {
            int j = tid + k * 1024;
            if (j < N) {
                float s = ssc[j];
                if (s > bs || (s == bs && j < bi)) { bs = s; bi = j; }
            }
        }
        // wave64 tree reduce
        for (int off = 32; off > 0; off >>= 1) {
            float s2 = __shfl_down(bs, off);
            int i2 = __shfl_down(bi, off);
            if (s2 > bs || (s2 == bs && i2 < bi)) { bs = s2; bi = i2; }
        }
        if ((tid & 63) == 0) {
            rs[tid >> 6] = bs;
            ri[tid >> 6] = bi;
        }
        __syncthreads();
        if (tid == 0) {
            float fs = rs[0];
            int fi = ri[0];
            for (int wv = 1; wv < 16; ++wv) {
                if (rs[wv] > fs || (rs[wv] == fs && ri[wv] < fi)) { fs = rs[wv]; fi = ri[wv]; }
            }
            out_idx[t] = fi;
            out_valid[t] = (fs > -INFINITY) ? 1.0f : 0.0f;
            swin = fi;
        }
        __syncthreads();

        int wi = swin;
        // broadcast winner box via (L1-cached) global read
        float wx1 = pbox[wi * 4 + 0];
        float wy1 = pbox[wi * 4 + 1];
        float wx2 = pbox[wi * 4 + 2];
        float wy2 = pbox[wi * 4 + 3];
        float war = (wx2 - wx1 + 1.0f) * (wy2 - wy1 + 1.0f);
#pragma unroll
        for (int k = 0; k < 6; ++k) {
            int j = tid + k * 1024;
            if (j < N) {
                float xx1 = fmaxf(wx1, x1[k]);
                float yy1 = fmaxf(wy1, y1[k]);
                float xx2 = fminf(wx2, x2[k]);
                float yy2 = fminf(wy2, y2[k]);
                float inter = fmaxf(xx2 - xx1 + 1.0f, 0.0f) * fmaxf(yy2 - yy1 + 1.0f, 0.0f);
                float iou = inter / (war + ar[k] - inter);
                if (iou > NMS_THRESH || j == wi) ssc[j] = -INFINITY;
            }
        }
        __syncthreads();
    }
}

// ---------------------------------------------------------------------------
// Kernel 3: gather outputs. One block per selected row.
// out layout: boxes [300*4] | scores [300*81] | masks [300*15876]
// ---------------------------------------------------------------------------
__global__ void gather_kernel(const float* __restrict__ pbox,
                              const float* __restrict__ scores,
                              const float* __restrict__ masks,
                              const int* __restrict__ idx,
                              const float* __restrict__ valid,
                              float* __restrict__ out) {
    int b = blockIdx.x;  // 0..PADDING-1
    int tid = threadIdx.x;
    int i = idx[b];
    float vf = valid[b];

    if (tid < 4) out[b * 4 + tid] = pbox[i * 4 + tid] * vf;
    if (tid < C) out[PADDING * 4 + b * C + tid] = scores[i * C + tid] * vf;

    const float4* src = (const float4*)(masks + (size_t)i * MASK_ELEMS);
    float4* dst = (float4*)(out + PADDING * 4 + PADDING * C + (size_t)b * MASK_ELEMS);
    for (int m = tid; m < MASK_ELEMS / 4; m += 256) {
        float4 v = src[m];
        dst[m] = make_float4(v.x * vf, v.y * vf, v.z * vf, v.w * vf);
    }
}

extern "C" void kernel_launch(void* const* d_in, const int* in_sizes, int n_in,
                              void* d_out, int out_size, void* d_ws, size_t ws_size,
                              hipStream_t stream) {
    const float* meta      = (const float*)d_in[0];
    const float* deltas    = (const float*)d_in[1];
    const float* proposals = (const float*)d_in[2];
    const float* scores    = (const float*)d_in[3];
    const float* masks     = (const float*)d_in[4];
    float* out = (float*)d_out;

    float* pbox  = (float*)d_ws;          // N*4 floats
    float* maxs  = pbox + N * 4;          // N floats
    int*   idx   = (int*)(maxs + N);      // PADDING ints
    float* valid = (float*)(idx + PADDING);  // PADDING floats

    decode_kernel<<<(N + 255) / 256, 256, 0, stream>>>(meta, deltas, proposals, scores, pbox, maxs);
    nms_kernel<<<1, 1024, 0, stream>>>(pbox, maxs, idx, valid);
    gather_kernel<<<PADDING, 256, 0, stream>>>(pbox, scores, masks, idx, valid, out);
}

// Round 2
// 612.084 us; speedup vs baseline: 2.5486x; 2.5486x over previous
//
#include <hip/hip_runtime.h>
#include <math.h>

#pragma STDC FP_CONTRACT OFF

#define N 6000
#define NPAD 6144
#define C 81
#define PADDING 300
#define NMS_THRESH 0.5f
#define MASK_ELEMS (14 * 14 * 81) /* 15876 */
#define MASK_W 96                 /* u64 words per mask row (94 used, 96 for 16B align) */
#define NCHUNK 8
#define CHUNK 750                 /* 6000 / 8 */
#define LOOK 8                    /* scan row-prefetch depth */

typedef unsigned long long u64;

// ---------------------------------------------------------------------------
// Kernel 1: per-proposal decode (identical math to the round-1 kernel that
// passed with absmax 0) + area + packed sort key.
// key = orderable(max_score) << 32 | ~i  -> u64 compare == (score desc, idx asc)
// ---------------------------------------------------------------------------
__global__ void decode_kernel(const float* __restrict__ meta,
                              const float* __restrict__ deltas,
                              const float* __restrict__ proposals,
                              const float* __restrict__ scores,
                              float* __restrict__ pbox,
                              float* __restrict__ area,
                              u64* __restrict__ skey) {
    int n = blockIdx.x * blockDim.x + threadIdx.x;
    if (n >= N) return;

    float Hm = meta[0], Wm = meta[1], scale = meta[2];

    float b0 = proposals[n * 4 + 0] / scale;
    float b1 = proposals[n * 4 + 1] / scale;
    float b2 = proposals[n * 4 + 2] / scale;
    float b3 = proposals[n * 4 + 3] / scale;
    float w = b2 - b0 + 1.0f;
    float h = b3 - b1 + 1.0f;
    float cx = b0 + 0.5f * w;
    float cy = b1 + 0.5f * h;

    const float* sr = scores + n * C;
    int top = 0;
    float best = sr[0];
    float ms = -INFINITY;  // max over classes 1..C-1
    for (int c = 1; c < C; ++c) {
        float s = sr[c];
        if (s > best) { best = s; top = c; }  // strict > == first occurrence
        ms = fmaxf(ms, s);
    }

    const float* dr = deltas + n * (4 * C) + 4 * top;
    float dx = dr[0], dy = dr[1], dw = dr[2], dh = dr[3];
    float pcx = dx * w + cx;
    float pcy = dy * h + cy;
    float pw = expf(dw) * w;
    float ph = expf(dh) * h;
    float x1 = pcx - 0.5f * pw;
    float y1 = pcy - 0.5f * ph;
    float x2 = pcx + 0.5f * pw;
    float y2 = pcy + 0.5f * ph;
    x1 = fminf(fmaxf(x1, 0.0f), Wm - 1.0f);
    y1 = fminf(fmaxf(y1, 0.0f), Hm - 1.0f);
    x2 = fminf(fmaxf(x2, 0.0f), Wm - 1.0f);
    y2 = fminf(fmaxf(y2, 0.0f), Hm - 1.0f);

    pbox[n * 4 + 0] = x1;
    pbox[n * 4 + 1] = y1;
    pbox[n * 4 + 2] = x2;
    pbox[n * 4 + 3] = y2;
    area[n] = (x2 - x1 + 1.0f) * (y2 - y1 + 1.0f);  // exact reference expression

    unsigned int b = __float_as_uint(ms);
    unsigned int u = b ^ ((b & 0x80000000u) ? 0xFFFFFFFFu : 0x80000000u);
    skey[n] = ((u64)u << 32) | (unsigned int)(~n);
}

// ---------------------------------------------------------------------------
// Kernel 2: brute-force rank (partial counts per key-chunk; no atomics).
// rank[i] = #{ j : key_j > key_i }  — keys are unique, so ranks are a perfect
// permutation implementing (score desc, index asc) order.
// ---------------------------------------------------------------------------
__global__ void rank_kernel(const u64* __restrict__ skey,
                            int* __restrict__ rank_part) {
    __shared__ u64 lk[CHUNK];
    int chunk = blockIdx.y;
    int t = threadIdx.x;
    int j0 = chunk * CHUNK;
    for (int j = t; j < CHUNK; j += 256) lk[j] = skey[j0 + j];
    __syncthreads();

    int i = blockIdx.x * 256 + t;
    if (i >= N) return;
    u64 mykey = skey[i];
    int cnt = 0;
    for (int j = 0; j < CHUNK; ++j) cnt += (lk[j] > mykey) ? 1 : 0;
    rank_part[chunk * NPAD + i] = cnt;
}

// ---------------------------------------------------------------------------
// Kernel 3: scatter into sorted order (SoA box arrays for the IoU kernel).
// ---------------------------------------------------------------------------
__global__ void scatter_kernel(const int* __restrict__ rank_part,
                               const float* __restrict__ pbox,
                               const float* __restrict__ area,
                               int* __restrict__ sidx,
                               float* __restrict__ sx1, float* __restrict__ sy1,
                               float* __restrict__ sx2, float* __restrict__ sy2,
                               float* __restrict__ sarea) {
    int i = blockIdx.x * blockDim.x + threadIdx.x;
    if (i >= N) return;
    int r = 0;
    for (int c = 0; c < NCHUNK; ++c) r += rank_part[c * NPAD + i];
    sidx[r] = i;
    sx1[r] = pbox[i * 4 + 0];
    sy1[r] = pbox[i * 4 + 1];
    sx2[r] = pbox[i * 4 + 2];
    sy2[r] = pbox[i * 4 + 3];
    sarea[r] = area[i];
}

// ---------------------------------------------------------------------------
// Kernel 4: suppression bitmask matrix over sorted positions.
// One wave per row p: lanes sweep 94 words of 64 cols; ballot assembles bits.
// Exact reference IoU: inter / (areas[p] + areas[q] - inter) > 0.5.
// Self bit (q==p): iou = a/a = 1.0 > 0.5, covers the (arange==i) term.
// Cols >= 6000 (word 93 high bits) produce garbage; the scan pre-marks them
// suppressed, and OR only adds — harmless.
// ---------------------------------------------------------------------------
__global__ void __launch_bounds__(256) iou_kernel(const float* __restrict__ sx1,
                                                  const float* __restrict__ sy1,
                                                  const float* __restrict__ sx2,
                                                  const float* __restrict__ sy2,
                                                  const float* __restrict__ sarea,
                                                  u64* __restrict__ mask) {
    int p = blockIdx.x * 4 + (threadIdx.x >> 6);
    int lane = threadIdx.x & 63;
    if (p >= N) return;

    float wx1 = sx1[p], wy1 = sy1[p], wx2 = sx2[p], wy2 = sy2[p];
    float war = sarea[p];
    u64* row = mask + (size_t)p * MASK_W;

    for (int w = 0; w < 94; ++w) {
        int q = w * 64 + lane;  // < 6144, arrays padded
        float xx1 = fmaxf(wx1, sx1[q]);
        float yy1 = fmaxf(wy1, sy1[q]);
        float xx2 = fminf(wx2, sx2[q]);
        float yy2 = fminf(wy2, sy2[q]);
        float inter = fmaxf(xx2 - xx1 + 1.0f, 0.0f) * fmaxf(yy2 - yy1 + 1.0f, 0.0f);
        float iou = inter / (war + sarea[q] - inter);
        u64 bal = __ballot(iou > NMS_THRESH);
        if (lane == 0) row[w] = bal;
    }
}

// ---------------------------------------------------------------------------
// Kernel 5: serial scan — single wave, suppressed-mask in registers
// (lane owns words 2*lane, 2*lane+1; words >= 94 and bits >= 6000 pre-set).
// Per kept step: ballot+ffs finds first zero bit -> kept position p;
// OR row p. LOOK-row register prefetch hides the row-load latency for
// consecutive kept positions (the common case).
// ---------------------------------------------------------------------------
__global__ void scan_kernel(const u64* __restrict__ mask,
                            const int* __restrict__ sidx,
                            int* __restrict__ out_idx,
                            float* __restrict__ out_valid) {
    int lane = threadIdx.x;
    int w0 = 2 * lane, w1 = 2 * lane + 1;

    u64 m_lo = (w0 < 93) ? 0ULL : (w0 == 93 ? 0xFFFF000000000000ULL : ~0ULL);
    u64 m_hi = (w1 < 93) ? 0ULL : (w1 == 93 ? 0xFFFF000000000000ULL : ~0ULL);

    u64 cx[LOOK], cy[LOOK];
#pragma unroll
    for (int k = 0; k < LOOK; ++k) { cx[k] = 0; cy[k] = 0; }
    int base = -1000000;

    int r = 0;
    while (r < PADDING) {
        u64 z0 = ~m_lo, z1 = ~m_hi;
        u64 bal = __ballot((z0 | z1) != 0ULL);
        if (bal == 0ULL) break;
        int lsrc = (int)__ffsll(bal) - 1;
        int local = (z0 != 0ULL) ? ((int)__ffsll(z0) - 1) : (64 + (int)__ffsll(z1) - 1);
        int p = __shfl(lane * 128 + local, lsrc);

        if (p > base + (LOOK - 1)) {
            base = p;
            if (lane < 48) {
#pragma unroll
                for (int k = 0; k < LOOK; ++k) {
                    int rowp = min(p + k, N - 1);
                    const u64* rp = mask + (size_t)rowp * MASK_W + 2 * lane;
                    cx[k] = rp[0];
                    cy[k] = rp[1];
                }
            }
        }
        int s = p - base;
        u64 vx = cx[0], vy = cy[0];
#pragma unroll
        for (int k = 1; k < LOOK; ++k) {
            if (s == k) { vx = cx[k]; vy = cy[k]; }
        }
        if (lane < 48) { m_lo |= vx; m_hi |= vy; }
        if (lane == 0) { out_idx[r] = sidx[p]; out_valid[r] = 1.0f; }
        ++r;
    }
    for (; r < PADDING; ++r) {
        if (lane == 0) { out_idx[r] = 0; out_valid[r] = 0.0f; }
    }
}

// ---------------------------------------------------------------------------
// Kernel 6: gather outputs. One block per selected row.
// out layout: boxes [300*4] | scores [300*81] | masks [300*15876]
// ---------------------------------------------------------------------------
__global__ void gather_kernel(const float* __restrict__ pbox,
                              const float* __restrict__ scores,
                              const float* __restrict__ masks,
                              const int* __restrict__ idx,
                              const float* __restrict__ valid,
                              float* __restrict__ out) {
    int b = blockIdx.x;  // 0..PADDING-1
    int tid = threadIdx.x;
    int i = idx[b];
    float vf = valid[b];

    if (tid < 4) out[b * 4 + tid] = pbox[i * 4 + tid] * vf;
    if (tid < C) out[PADDING * 4 + b * C + tid] = scores[i * C + tid] * vf;

    const float4* src = (const float4*)(masks + (size_t)i * MASK_ELEMS);
    float4* dst = (float4*)(out + PADDING * 4 + PADDING * C + (size_t)b * MASK_ELEMS);
    for (int m = tid; m < MASK_ELEMS / 4; m += 256) {
        float4 v = src[m];
        dst[m] = make_float4(v.x * vf, v.y * vf, v.z * vf, v.w * vf);
    }
}

extern "C" void kernel_launch(void* const* d_in, const int* in_sizes, int n_in,
                              void* d_out, int out_size, void* d_ws, size_t ws_size,
                              hipStream_t stream) {
    const float* meta      = (const float*)d_in[0];
    const float* deltas    = (const float*)d_in[1];
    const float* proposals = (const float*)d_in[2];
    const float* scores    = (const float*)d_in[3];
    const float* masks     = (const float*)d_in[4];
    float* out = (float*)d_out;

    // Workspace layout (bytes). Total ~5.13 MB.
    char* ws = (char*)d_ws;
    u64*   mask      = (u64*)(ws);                       // 6000*96*8 = 4,608,000
    u64*   skey      = (u64*)(ws + 4608000);             // 6144*8    =    49,152
    float* pbox      = (float*)(ws + 4657152);           // 6000*4*4  =    96,000
    float* area      = (float*)(ws + 4753152);           // 6000*4    =    24,000
    int*   rank_part = (int*)(ws + 4777152);             // 8*6144*4  =   196,608
    int*   sidx      = (int*)(ws + 4973760);             // 6144*4    =    24,576
    float* sx1       = (float*)(ws + 4998336);           // 6144*4 each
    float* sy1       = (float*)(ws + 5022912);
    float* sx2       = (float*)(ws + 5047488);
    float* sy2       = (float*)(ws + 5072064);
    float* sarea     = (float*)(ws + 5096640);
    int*   out_idx   = (int*)(ws + 5121216);             // 300*4
    float* out_valid = (float*)(ws + 5122416);           // 300*4

    decode_kernel<<<24, 256, 0, stream>>>(meta, deltas, proposals, scores, pbox, area, skey);
    rank_kernel<<<dim3(24, NCHUNK), 256, 0, stream>>>(skey, rank_part);
    scatter_kernel<<<24, 256, 0, stream>>>(rank_part, pbox, area, sidx, sx1, sy1, sx2, sy2, sarea);
    iou_kernel<<<1500, 256, 0, stream>>>(sx1, sy1, sx2, sy2, sarea, mask);
    scan_kernel<<<1, 64, 0, stream>>>(mask, sidx, out_idx, out_valid);
    gather_kernel<<<PADDING, 256, 0, stream>>>(pbox, scores, masks, out_idx, out_valid, out);
}